// Round 9
// baseline (369.944 us; speedup 1.0000x reference)
//
#include <hip/hip_runtime.h>

#define NN 8192
#define DD 256
#define BM 128                 // rows per block
#define BK 64                  // j per K-step
#define JSPLIT 4
#define JCH (NN / JSPLIT)      // 2048 j per block
#define NT (JCH / BK)          // 32 K-steps

typedef __attribute__((ext_vector_type(8))) short short8;   // 8 bf16 MFMA frag
typedef __attribute__((ext_vector_type(4))) float f32x4;    // MFMA accumulator

__device__ __forceinline__ short f2bf(float x) {
    union { float f; unsigned u; } v; v.f = x;
    unsigned r = (v.u + 0x7FFFu + ((v.u >> 16) & 1u)) >> 16;  // RNE
    return (short)r;
}
__device__ __forceinline__ float bf2f(short b) {
    union { float f; unsigned u; } v; v.u = ((unsigned)(unsigned short)b) << 16;
    return v.f;
}

// Barrier that does NOT drain vmcnt (in-flight global prefetch survives).
__device__ __forceinline__ void barrier_keep_vmem() {
    asm volatile("s_waitcnt lgkmcnt(0)" ::: "memory");
    __builtin_amdgcn_s_barrier();
    asm volatile("" ::: "memory");
}

// Kernel 1: h = x@W (fp32); emit hT (bf16, [D][N]), e_src, e_dst. (unchanged)
__global__ __launch_bounds__(256) void gat_prep(
    const float* __restrict__ x, const float* __restrict__ W,
    const float* __restrict__ a,
    short* __restrict__ hT, float* __restrict__ e_src, float* __restrict__ e_dst)
{
    __shared__ float x_s[32][260];          // +4 pad
    __shared__ float W_s[2][16][256];       // 16-row W chunk, double-buffered
    const int t  = threadIdx.x;
    const int ib = blockIdx.x * 32;

    #pragma unroll
    for (int rep = 0; rep < 8; ++rep) {
        int fi = rep * 256 + t;
        int r  = fi >> 6;
        int c4 = (fi & 63) * 4;
        float4 v = *(const float4*)(x + (size_t)(ib + r) * DD + c4);
        *(float4*)&x_s[r][c4] = v;
    }
    float4 wp[4];
    #pragma unroll
    for (int q = 0; q < 4; ++q) {
        int fi = q * 256 + t;
        wp[q] = *(const float4*)(W + (size_t)(fi >> 6) * DD + (fi & 63) * 4);
    }
    barrier_keep_vmem();

    const int il = t >> 3;
    const int dg = (t & 7) * 4;
    f32x4 acc[8];
    #pragma unroll
    for (int m = 0; m < 8; ++m) acc[m] = (f32x4){0.f, 0.f, 0.f, 0.f};

    for (int kc = 0; kc < 16; ++kc) {
        const int b = kc & 1;
        #pragma unroll
        for (int q = 0; q < 4; ++q) {
            int fi = q * 256 + t;
            *(float4*)&W_s[b][fi >> 6][(fi & 63) * 4] = wp[q];
        }
        if (kc < 15) {
            #pragma unroll
            for (int q = 0; q < 4; ++q) {
                int fi = q * 256 + t;
                wp[q] = *(const float4*)(W + (size_t)((kc + 1) * 16 + (fi >> 6)) * DD + (fi & 63) * 4);
            }
        }
        barrier_keep_vmem();
        #pragma unroll
        for (int kl = 0; kl < 16; ++kl) {
            float xv = x_s[il][kc * 16 + kl];
            #pragma unroll
            for (int m = 0; m < 8; ++m) {
                float4 wv = *(const float4*)&W_s[b][kl][m * 32 + dg];
                acc[m].x += xv * wv.x; acc[m].y += xv * wv.y;
                acc[m].z += xv * wv.z; acc[m].w += xv * wv.w;
            }
        }
    }

    const int ig = ib + il;
    float p1 = 0.f, p2 = 0.f;
    #pragma unroll
    for (int m = 0; m < 8; ++m) {
        #pragma unroll
        for (int j = 0; j < 4; ++j) {
            int col = m * 32 + dg + j;
            float hv = acc[m][j];
            p1 += hv * a[col];
            p2 += hv * a[DD + col];
            hT[(size_t)col * NN + ig] = f2bf(hv);
        }
    }
    p1 += __shfl_xor(p1, 1); p1 += __shfl_xor(p1, 2); p1 += __shfl_xor(p1, 4);
    p2 += __shfl_xor(p2, 1); p2 += __shfl_xor(p2, 2); p2 += __shfl_xor(p2, 4);
    if ((t & 7) == 0) { e_src[ig] = p1; e_dst[ig] = p2; }
}

// Kernel 2: m97-structure fused masked-softmax GEMM with adj fused in.
// Block (rb = bid>>2, jc = bid&3): rows [rb*128,+128), j in [jc*2048,+2048).
// hT tile [256 d][64 j] staged to LDS via global_load_lds (dbuf, XOR-swizzled
// source, T2/m173). A-frags (exp weights) built in-register from streamed
// raw adj (full-line coalesced; adj read ONCE chip-wide -> HBM floor overlaps
// compute). Counted vmcnt(24) before the barrier (stage stays in flight).
__global__ __launch_bounds__(512, 2) void gat_main(
    const int* __restrict__ adj, const short* __restrict__ hT,
    const float* __restrict__ e_src, const float* __restrict__ e_dst,
    float* __restrict__ num, float* __restrict__ den_part)
{
    __shared__ __align__(16) short Bt[2][256 * BK];   // 2 x 32 KB hT tile

    const int t    = threadIdx.x;
    const int lane = t & 63;
    const int w    = t >> 6;
    const int wr   = w >> 2;            // row half (0-1)
    const int wc   = w & 3;             // col quarter (0-3)
    const int jc   = blockIdx.x & (JSPLIT - 1);
    const int rb   = blockIdx.x >> 2;
    const int jb   = jc * JCH;

    const int arow = lane & 15;
    const int kq   = lane >> 4;         // 0..3
    const int kg8  = kq * 8;
    const int cb   = wc * 64;
    const int rbl  = rb * BM + wr * 64;

    // staging geometry: wave w stages tile rows [w*32, w*32+32), 4 insts of 8 rows
    const int lrow = lane >> 3;         // 0..7 within inst
    const int lblk = lane & 7;          // 16B block within 128B row

    float es[4];
    const int* arp[4];
    #pragma unroll
    for (int mrt = 0; mrt < 4; ++mrt) {
        int r = rbl + mrt * 16 + arow;
        es[mrt]  = e_src[r];
        arp[mrt] = adj + (size_t)r * NN + jb + kg8;
    }
    const float* pep = e_dst + jb + kg8;

    f32x4 acc[4][4];
    #pragma unroll
    for (int mrt = 0; mrt < 4; ++mrt)
        #pragma unroll
        for (int nb = 0; nb < 4; ++nb) acc[mrt][nb] = (f32x4){0.f, 0.f, 0.f, 0.f};
    float ds[4] = {0.f, 0.f, 0.f, 0.f};

    int4   pa[4][2][2];                 // adj prefetch (16 int4)
    float4 pe[2][2];                    // e_dst prefetch (4 float4)
    short8 af[4][2];                    // A-frags

    // stage tile n_ into buffer b_: linear LDS dest, XOR-pre-swizzled global src
#define STAGE(b_, n_) do {                                                      \
        int jt_ = jb + (n_) * BK;                                               \
        _Pragma("unroll")                                                       \
        for (int q = 0; q < 4; ++q) {                                           \
            int d_ = w * 32 + q * 8 + lrow;                                     \
            const short* src_ = hT + (size_t)d_ * NN + jt_ + ((lblk ^ (d_ & 7)) * 8); \
            __builtin_amdgcn_global_load_lds(                                   \
                (const __attribute__((address_space(1))) void*)src_,            \
                (__attribute__((address_space(3))) void*)&Bt[b_][(w * 32 + q * 8) * BK], \
                16, 0, 0);                                                      \
        }                                                                       \
        __builtin_amdgcn_sched_barrier(0);                                      \
    } while (0)

#define PREFETCH(n_) do {                                                       \
        int j0_ = (n_) * BK;                                                    \
        _Pragma("unroll")                                                       \
        for (int mrt = 0; mrt < 4; ++mrt)                                       \
            _Pragma("unroll")                                                   \
            for (int kt = 0; kt < 2; ++kt) {                                    \
                pa[mrt][kt][0] = *(const int4*)(arp[mrt] + j0_ + kt * 32);      \
                pa[mrt][kt][1] = *(const int4*)(arp[mrt] + j0_ + kt * 32 + 4);  \
            }                                                                   \
        _Pragma("unroll")                                                       \
        for (int kt = 0; kt < 2; ++kt) {                                        \
            pe[kt][0] = *(const float4*)(pep + j0_ + kt * 32);                  \
            pe[kt][1] = *(const float4*)(pep + j0_ + kt * 32 + 4);              \
        }                                                                       \
    } while (0)

#define ABUILD do {                                                             \
        _Pragma("unroll")                                                       \
        for (int mrt = 0; mrt < 4; ++mrt)                                       \
            _Pragma("unroll")                                                   \
            for (int kt = 0; kt < 2; ++kt) {                                    \
                const int*   av = (const int*)&pa[mrt][kt][0];                  \
                const float* ev = (const float*)&pe[kt][0];                     \
                _Pragma("unroll")                                               \
                for (int i = 0; i < 8; ++i) {                                   \
                    float s = es[mrt] + ev[i];                                  \
                    float l = s > 0.f ? s : 0.01f * s;                          \
                    float wv = av[i] > 0 ? __expf(l) : 0.f;                     \
                    short bb = f2bf(wv);                                        \
                    af[mrt][kt][i] = bb;                                        \
                    ds[mrt] += bf2f(bb);   /* denom = SAME bf16 weights */      \
                }                                                               \
            }                                                                   \
    } while (0)

#define COMPUTE(b_) do {                                                        \
        _Pragma("unroll")                                                       \
        for (int nb = 0; nb < 4; ++nb) {                                        \
            int d_ = cb + nb * 16 + arow;                                       \
            const short* rowp_ = &Bt[b_][d_ * BK];                              \
            _Pragma("unroll")                                                   \
            for (int kt = 0; kt < 2; ++kt) {                                    \
                short8 bf = *(const short8*)(rowp_ + (((kt * 4 + kq) ^ (arow & 7)) * 8)); \
                _Pragma("unroll")                                               \
                for (int mrt = 0; mrt < 4; ++mrt)                               \
                    acc[mrt][nb] = __builtin_amdgcn_mfma_f32_16x16x32_bf16(     \
                        af[mrt][kt], bf, acc[mrt][nb], 0, 0, 0);                \
            }                                                                   \
        }                                                                       \
    } while (0)

    // vmcnt(24): keep this iteration's 24 loads (4 stage + 16 adj + 4 e) in
    // flight; everything older (incl. current tile's global_load_lds) retired.
#define KSTEP(CUR, n_) do {                                                     \
        STAGE(CUR ^ 1, ((n_) + 1) & (NT - 1));                                  \
        ABUILD;                                                                 \
        PREFETCH(((n_) + 1) & (NT - 1));                                        \
        asm volatile("s_waitcnt vmcnt(24)" ::: "memory");                       \
        __builtin_amdgcn_s_barrier();                                           \
        asm volatile("" ::: "memory");                                          \
        COMPUTE(CUR);                                                           \
        barrier_keep_vmem();                                                    \
    } while (0)

    STAGE(0, 0);
    PREFETCH(0);
    for (int n = 0; n < NT; n += 2) {
        KSTEP(0, n);
        KSTEP(1, n + 1);
    }
#undef KSTEP
#undef COMPUTE
#undef ABUILD
#undef PREFETCH
#undef STAGE

    // partial denom: reduce over the 4 kq groups; one col-wave writes
    #pragma unroll
    for (int mrt = 0; mrt < 4; ++mrt) {
        float dd = ds[mrt];
        dd += __shfl_xor(dd, 16);
        dd += __shfl_xor(dd, 32);
        if (wc == 0 && lane < 16)
            den_part[(size_t)jc * NN + rbl + mrt * 16 + lane] = dd;
    }

    // partial numerator: row = rbl + mrt*16 + kq*4 + r, col = cb + nb*16 + arow
    float* np = num + (size_t)jc * NN * DD;
    #pragma unroll
    for (int mrt = 0; mrt < 4; ++mrt)
        #pragma unroll
        for (int nb = 0; nb < 4; ++nb) {
            size_t o = (size_t)(rbl + mrt * 16 + kq * 4) * DD + cb + nb * 16 + arow;
            #pragma unroll
            for (int r = 0; r < 4; ++r)
                np[o + (size_t)r * DD] = acc[mrt][nb][r];
        }
}

// Kernel 3: out = elu( (sum_p num[p]) / (sum_p den[p]) ). Streaming ~40MB.
__global__ __launch_bounds__(256) void gat_epi(
    float* __restrict__ out, const float* __restrict__ num,
    const float* __restrict__ den_part)
{
    int idx = blockIdx.x * 256 + threadIdx.x;       // float4 index; 64 per row
    int row = idx >> 6;
    float d = 0.f;
    #pragma unroll
    for (int p = 0; p < JSPLIT; ++p) d += den_part[(size_t)p * NN + row];
    float4 s = {0.f, 0.f, 0.f, 0.f};
    #pragma unroll
    for (int p = 0; p < JSPLIT; ++p) {
        float4 v = ((const float4*)(num + (size_t)p * NN * DD))[idx];
        s.x += v.x; s.y += v.y; s.z += v.z; s.w += v.w;
    }
    float inv = 1.f / d;
    float4 o;
    o.x = s.x * inv; o.x = o.x > 0.f ? o.x : expm1f(o.x);
    o.y = s.y * inv; o.y = o.y > 0.f ? o.y : expm1f(o.y);
    o.z = s.z * inv; o.z = o.z > 0.f ? o.z : expm1f(o.z);
    o.w = s.w * inv; o.w = o.w > 0.f ? o.w : expm1f(o.w);
    ((float4*)out)[idx] = o;
}

extern "C" void kernel_launch(void* const* d_in, const int* in_sizes, int n_in,
                              void* d_out, int out_size, void* d_ws, size_t ws_size,
                              hipStream_t stream) {
    const float* x   = (const float*)d_in[0];
    const int*   adj = (const int*)d_in[1];
    const float* W   = (const float*)d_in[2];
    const float* a   = (const float*)d_in[3];
    float* out = (float*)d_out;

    // ws: hT 4MB | e_src 32KB | e_dst 32KB | den 128KB | num 32MB
    char* w0 = (char*)d_ws;
    short* hT   = (short*)w0;
    float* esrc = (float*)(w0 + (size_t)DD * NN * 2);
    float* edst = esrc + NN;
    float* den  = edst + NN;
    float* num  = den + (size_t)JSPLIT * NN;

    gat_prep<<<dim3(NN / 32), dim3(256), 0, stream>>>(x, W, a, hT, esrc, edst);
    gat_main<<<dim3((NN / BM) * JSPLIT), dim3(512), 0, stream>>>(
        adj, hT, esrc, edst, num, den);
    gat_epi<<<dim3(NN * DD / 4 / 256), dim3(256), 0, stream>>>(out, num, den);
}

// Round 10
// 258.345 us; speedup vs baseline: 1.4320x; 1.4320x over previous
//
#include <hip/hip_runtime.h>

#define NN 8192
#define DD 256
#define BM 128                 // rows per block
#define BK 64                  // j per K-step
#define JSPLIT 4
#define JCH (NN / JSPLIT)      // 2048 j per block
#define NT (JCH / BK)          // 32 K-steps

typedef __attribute__((ext_vector_type(8))) short short8;   // 8 bf16 MFMA frag
typedef __attribute__((ext_vector_type(4))) float f32x4;    // MFMA accumulator

__device__ __forceinline__ short f2bf(float x) {
    union { float f; unsigned u; } v; v.f = x;
    unsigned r = (v.u + 0x7FFFu + ((v.u >> 16) & 1u)) >> 16;  // RNE
    return (short)r;
}
__device__ __forceinline__ float bf2f(short b) {
    union { float f; unsigned u; } v; v.u = ((unsigned)(unsigned short)b) << 16;
    return v.f;
}

// Barrier that does NOT drain vmcnt (in-flight global prefetch survives).
__device__ __forceinline__ void barrier_keep_vmem() {
    asm volatile("s_waitcnt lgkmcnt(0)" ::: "memory");
    __builtin_amdgcn_s_barrier();
    asm volatile("" ::: "memory");
}

// Kernel 0: bit-pack adj. adj [NN][NN] int32 -> bits [NN][NN/32] uint32.
// THE single streaming read of adj (256MB, 4KB-contiguous per wave = HBM
// efficient; measured ~42us). R9 proved fusing this into the GEMM drops
// HBM efficiency 6x (16-row scattered 64B segments) -- keep it separate.
__global__ __launch_bounds__(256) void gat_pack(
    const int* __restrict__ adj, unsigned* __restrict__ bits)
{
    const int t   = threadIdx.x;
    const int row = blockIdx.x;
    const int* ar = adj + (size_t)row * NN;
    unsigned* br  = bits + (size_t)row * (NN / 32);
    #pragma unroll
    for (int i = 0; i < 8; ++i) {
        int j0 = i * 1024 + t * 4;
        int4 v = *(const int4*)(ar + j0);
        unsigned nib = (v.x > 0 ? 1u : 0u) | (v.y > 0 ? 2u : 0u)
                     | (v.z > 0 ? 4u : 0u) | (v.w > 0 ? 8u : 0u);
        unsigned word = nib << ((t & 7) * 4);
        word |= __shfl_xor((int)word, 1);
        word |= __shfl_xor((int)word, 2);
        word |= __shfl_xor((int)word, 4);
        if ((t & 7) == 0) br[i * 32 + (t >> 3)] = word;
    }
}

// Kernel 1: h = x@W (fp32); emit hT (bf16, [D][N]), e_src, e_dst.
__global__ __launch_bounds__(256) void gat_prep(
    const float* __restrict__ x, const float* __restrict__ W,
    const float* __restrict__ a,
    short* __restrict__ hT, float* __restrict__ e_src, float* __restrict__ e_dst)
{
    __shared__ float x_s[32][260];          // +4 pad
    __shared__ float W_s[2][16][256];       // 16-row W chunk, double-buffered
    const int t  = threadIdx.x;
    const int ib = blockIdx.x * 32;

    #pragma unroll
    for (int rep = 0; rep < 8; ++rep) {
        int fi = rep * 256 + t;
        int r  = fi >> 6;
        int c4 = (fi & 63) * 4;
        float4 v = *(const float4*)(x + (size_t)(ib + r) * DD + c4);
        *(float4*)&x_s[r][c4] = v;
    }
    float4 wp[4];
    #pragma unroll
    for (int q = 0; q < 4; ++q) {
        int fi = q * 256 + t;
        wp[q] = *(const float4*)(W + (size_t)(fi >> 6) * DD + (fi & 63) * 4);
    }
    barrier_keep_vmem();

    const int il = t >> 3;
    const int dg = (t & 7) * 4;
    f32x4 acc[8];
    #pragma unroll
    for (int m = 0; m < 8; ++m) acc[m] = (f32x4){0.f, 0.f, 0.f, 0.f};

    for (int kc = 0; kc < 16; ++kc) {
        const int b = kc & 1;
        #pragma unroll
        for (int q = 0; q < 4; ++q) {
            int fi = q * 256 + t;
            *(float4*)&W_s[b][fi >> 6][(fi & 63) * 4] = wp[q];
        }
        if (kc < 15) {
            #pragma unroll
            for (int q = 0; q < 4; ++q) {
                int fi = q * 256 + t;
                wp[q] = *(const float4*)(W + (size_t)((kc + 1) * 16 + (fi >> 6)) * DD + (fi & 63) * 4);
            }
        }
        barrier_keep_vmem();
        #pragma unroll
        for (int kl = 0; kl < 16; ++kl) {
            float xv = x_s[il][kc * 16 + kl];
            #pragma unroll
            for (int m = 0; m < 8; ++m) {
                float4 wv = *(const float4*)&W_s[b][kl][m * 32 + dg];
                acc[m].x += xv * wv.x; acc[m].y += xv * wv.y;
                acc[m].z += xv * wv.z; acc[m].w += xv * wv.w;
            }
        }
    }

    const int ig = ib + il;
    float p1 = 0.f, p2 = 0.f;
    #pragma unroll
    for (int m = 0; m < 8; ++m) {
        #pragma unroll
        for (int j = 0; j < 4; ++j) {
            int col = m * 32 + dg + j;
            float hv = acc[m][j];
            p1 += hv * a[col];
            p2 += hv * a[DD + col];
            hT[(size_t)col * NN + ig] = f2bf(hv);
        }
    }
    p1 += __shfl_xor(p1, 1); p1 += __shfl_xor(p1, 2); p1 += __shfl_xor(p1, 4);
    p2 += __shfl_xor(p2, 1); p2 += __shfl_xor(p2, 2); p2 += __shfl_xor(p2, 4);
    if ((t & 7) == 0) { e_src[ig] = p1; e_dst[ig] = p2; }
}

// Kernel 2: m97-structure fused masked-softmax GEMM, bitmask masks.
// Block (rb = bid>>2, jc = bid&3): rows [rb*128,+128), j in [jc*2048,+2048).
// hT tile [256 d][64 j] staged to LDS via global_load_lds (dbuf, XOR-swizzled
// source + swizzled ds_read; R9-verified). A-frags (exp weights) built
// in-register from L3-resident bits + e values. Counted vmcnt(12) before the
// barrier: the 12 newest loads (next stage 4 + masks 4 + e 4) stay in flight,
// everything older (current tile's stage) is drained.
__global__ __launch_bounds__(512, 2) void gat_main(
    const unsigned* __restrict__ bits, const short* __restrict__ hT,
    const float* __restrict__ e_src, const float* __restrict__ e_dst,
    float* __restrict__ num, float* __restrict__ den_part)
{
    __shared__ __align__(16) short Bt[2][256 * BK];   // 2 x 32 KB hT tile

    const int t    = threadIdx.x;
    const int lane = t & 63;
    const int w    = t >> 6;
    const int wr   = w >> 2;            // row half (0-1)
    const int wc   = w & 3;             // col quarter (0-3)
    const int jc   = blockIdx.x & (JSPLIT - 1);
    const int rb   = blockIdx.x >> 2;
    const int jb   = jc * JCH;

    const int arow = lane & 15;
    const int kq   = lane >> 4;         // 0..3
    const int kg8  = kq * 8;
    const int cb   = wc * 64;
    const int rbl  = rb * BM + wr * 64;

    // staging geometry: wave w stages tile rows [w*32, w*32+32), 4 insts of 8 rows
    const int lrow = lane >> 3;         // 0..7 within inst
    const int lblk = lane & 7;          // 16B block within 128B row

    float es[4];
    const unsigned* brp[4];
    #pragma unroll
    for (int mrt = 0; mrt < 4; ++mrt) {
        int r = rbl + mrt * 16 + arow;
        es[mrt]  = e_src[r];
        brp[mrt] = bits + (size_t)r * (NN / 32) + (jb >> 5);
    }
    const float* pep = e_dst + jb + kg8;

    f32x4 acc[4][4];
    #pragma unroll
    for (int mrt = 0; mrt < 4; ++mrt)
        #pragma unroll
        for (int nb = 0; nb < 4; ++nb) acc[mrt][nb] = (f32x4){0.f, 0.f, 0.f, 0.f};
    float ds[4] = {0.f, 0.f, 0.f, 0.f};

    int2   pm[4];                       // mask prefetch (2 words = 64 j per row)
    float4 pe[2][2];                    // e_dst prefetch
    short8 af[4][2];                    // A-frags

    // stage tile n_ into buffer b_: linear LDS dest, XOR-pre-swizzled global src
#define STAGE(b_, n_) do {                                                      \
        int jt_ = jb + (n_) * BK;                                               \
        _Pragma("unroll")                                                       \
        for (int q = 0; q < 4; ++q) {                                           \
            int d_ = w * 32 + q * 8 + lrow;                                     \
            const short* src_ = hT + (size_t)d_ * NN + jt_ + ((lblk ^ (d_ & 7)) * 8); \
            __builtin_amdgcn_global_load_lds(                                   \
                (const __attribute__((address_space(1))) void*)src_,            \
                (__attribute__((address_space(3))) void*)&Bt[b_][(w * 32 + q * 8) * BK], \
                16, 0, 0);                                                      \
        }                                                                       \
        __builtin_amdgcn_sched_barrier(0);                                      \
    } while (0)

#define PREFETCH(n_) do {                                                       \
        _Pragma("unroll")                                                       \
        for (int mrt = 0; mrt < 4; ++mrt)                                       \
            pm[mrt] = *(const int2*)(brp[mrt] + (n_) * 2);                      \
        int j0_ = (n_) * BK;                                                    \
        _Pragma("unroll")                                                       \
        for (int kt = 0; kt < 2; ++kt) {                                        \
            pe[kt][0] = *(const float4*)(pep + j0_ + kt * 32);                  \
            pe[kt][1] = *(const float4*)(pep + j0_ + kt * 32 + 4);              \
        }                                                                       \
    } while (0)

#define ABUILD do {                                                             \
        _Pragma("unroll")                                                       \
        for (int mrt = 0; mrt < 4; ++mrt)                                       \
            _Pragma("unroll")                                                   \
            for (int kt = 0; kt < 2; ++kt) {                                    \
                unsigned wm = kt ? (unsigned)pm[mrt].y : (unsigned)pm[mrt].x;   \
                const float* ev = (const float*)&pe[kt][0];                     \
                _Pragma("unroll")                                               \
                for (int i = 0; i < 8; ++i) {                                   \
                    float s = es[mrt] + ev[i];                                  \
                    float l = s > 0.f ? s : 0.01f * s;                          \
                    float wv = ((wm >> (kg8 + i)) & 1u) ? __expf(l) : 0.f;      \
                    short bb = f2bf(wv);                                        \
                    af[mrt][kt][i] = bb;                                        \
                    ds[mrt] += bf2f(bb);   /* denom = SAME bf16 weights */      \
                }                                                               \
            }                                                                   \
    } while (0)

#define COMPUTE(b_) do {                                                        \
        _Pragma("unroll")                                                       \
        for (int nb = 0; nb < 4; ++nb) {                                        \
            int d_ = cb + nb * 16 + arow;                                       \
            const short* rowp_ = &Bt[b_][d_ * BK];                              \
            _Pragma("unroll")                                                   \
            for (int kt = 0; kt < 2; ++kt) {                                    \
                short8 bf = *(const short8*)(rowp_ + (((kt * 4 + kq) ^ (arow & 7)) * 8)); \
                _Pragma("unroll")                                               \
                for (int mrt = 0; mrt < 4; ++mrt)                               \
                    acc[mrt][nb] = __builtin_amdgcn_mfma_f32_16x16x32_bf16(     \
                        af[mrt][kt], bf, acc[mrt][nb], 0, 0, 0);                \
            }                                                                   \
        }                                                                       \
    } while (0)

#define KSTEP(CUR, n_) do {                                                     \
        STAGE(CUR ^ 1, ((n_) + 1) & (NT - 1));                                  \
        ABUILD;                                                                 \
        PREFETCH(((n_) + 1) & (NT - 1));                                        \
        asm volatile("s_waitcnt vmcnt(12)" ::: "memory");                       \
        __builtin_amdgcn_s_barrier();                                           \
        asm volatile("" ::: "memory");                                          \
        COMPUTE(CUR);                                                           \
        barrier_keep_vmem();                                                    \
    } while (0)

    STAGE(0, 0);
    PREFETCH(0);
    for (int n = 0; n < NT; n += 2) {
        KSTEP(0, n);
        KSTEP(1, n + 1);
    }
#undef KSTEP
#undef COMPUTE
#undef ABUILD
#undef PREFETCH
#undef STAGE

    // partial denom: reduce over the 4 kq groups; one col-wave writes
    #pragma unroll
    for (int mrt = 0; mrt < 4; ++mrt) {
        float dd = ds[mrt];
        dd += __shfl_xor(dd, 16);
        dd += __shfl_xor(dd, 32);
        if (wc == 0 && lane < 16)
            den_part[(size_t)jc * NN + rbl + mrt * 16 + lane] = dd;
    }

    // partial numerator: row = rbl + mrt*16 + kq*4 + r, col = cb + nb*16 + arow
    float* np = num + (size_t)jc * NN * DD;
    #pragma unroll
    for (int mrt = 0; mrt < 4; ++mrt)
        #pragma unroll
        for (int nb = 0; nb < 4; ++nb) {
            size_t o = (size_t)(rbl + mrt * 16 + kq * 4) * DD + cb + nb * 16 + arow;
            #pragma unroll
            for (int r = 0; r < 4; ++r)
                np[o + (size_t)r * DD] = acc[mrt][nb][r];
        }
}

// Kernel 3: out = elu( (sum_p num[p]) / (sum_p den[p]) ). Streaming ~40MB.
__global__ __launch_bounds__(256) void gat_epi(
    float* __restrict__ out, const float* __restrict__ num,
    const float* __restrict__ den_part)
{
    int idx = blockIdx.x * 256 + threadIdx.x;       // float4 index; 64 per row
    int row = idx >> 6;
    float d = 0.f;
    #pragma unroll
    for (int p = 0; p < JSPLIT; ++p) d += den_part[(size_t)p * NN + row];
    float4 s = {0.f, 0.f, 0.f, 0.f};
    #pragma unroll
    for (int p = 0; p < JSPLIT; ++p) {
        float4 v = ((const float4*)(num + (size_t)p * NN * DD))[idx];
        s.x += v.x; s.y += v.y; s.z += v.z; s.w += v.w;
    }
    float inv = 1.f / d;
    float4 o;
    o.x = s.x * inv; o.x = o.x > 0.f ? o.x : expm1f(o.x);
    o.y = s.y * inv; o.y = o.y > 0.f ? o.y : expm1f(o.y);
    o.z = s.z * inv; o.z = o.z > 0.f ? o.z : expm1f(o.z);
    o.w = s.w * inv; o.w = o.w > 0.f ? o.w : expm1f(o.w);
    ((float4*)out)[idx] = o;
}

extern "C" void kernel_launch(void* const* d_in, const int* in_sizes, int n_in,
                              void* d_out, int out_size, void* d_ws, size_t ws_size,
                              hipStream_t stream) {
    const float* x   = (const float*)d_in[0];
    const int*   adj = (const int*)d_in[1];
    const float* W   = (const float*)d_in[2];
    const float* a   = (const float*)d_in[3];
    float* out = (float*)d_out;

    // ws: hT 4MB | e_src 32KB | e_dst 32KB | bits 8MB | den 128KB | num 32MB
    char* w0 = (char*)d_ws;
    short* hT      = (short*)w0;
    float* esrc    = (float*)(w0 + (size_t)DD * NN * 2);
    float* edst    = esrc + NN;
    unsigned* bits = (unsigned*)(edst + NN);
    float* den     = (float*)((char*)bits + (size_t)NN * (NN / 32) * 4);
    float* num     = den + (size_t)JSPLIT * NN;

    gat_pack<<<dim3(NN), dim3(256), 0, stream>>>(adj, bits);
    gat_prep<<<dim3(NN / 32), dim3(256), 0, stream>>>(x, W, a, hT, esrc, edst);
    gat_main<<<dim3((NN / BM) * JSPLIT), dim3(512), 0, stream>>>(
        bits, hT, esrc, edst, num, den);
    gat_epi<<<dim3(NN * DD / 4 / 256), dim3(256), 0, stream>>>(out, num, den);
}